// Round 3
// baseline (185.293 us; speedup 1.0000x reference)
//
#include <hip/hip_runtime.h>
#include <stdint.h>

#define LOG2E 1.44269504088896340736f

using bf16x8 = __attribute__((ext_vector_type(8))) short;  // 8 bf16 (4 VGPRs)
using f32x4  = __attribute__((ext_vector_type(4))) float;

__device__ __forceinline__ ushort f2bf(float f) {
  union { float f; uint32_t u; } v; v.f = f;
  uint32_t u = v.u;
  u += 0x7FFFu + ((u >> 16) & 1u);   // RNE
  return (ushort)(u >> 16);
}
__device__ __forceinline__ float bf2f(ushort b) {
  union { uint32_t u; float f; } v; v.u = ((uint32_t)b) << 16;
  return v.f;
}

__device__ __forceinline__ void load_lds16(const void* g, void* l) {
  __builtin_amdgcn_global_load_lds(
      (const __attribute__((address_space(1))) void*)g,
      (__attribute__((address_space(3))) void*)l, 16, 0, 0);
}

// out[row] = dot(mat[row, 0:512], vec[0:512]); 4 rows per 256-thread block
__global__ void rowdot(const float* __restrict__ mat, const float* __restrict__ vec,
                       float* __restrict__ out) {
  int w = threadIdx.x >> 6, l = threadIdx.x & 63;
  int row = blockIdx.x * 4 + w;
  const float4* mp = (const float4*)(mat + row * 512 + l * 8);
  const float4* vp = (const float4*)(vec + l * 8);
  float4 a0 = mp[0], a1 = mp[1];
  float4 b0 = vp[0], b1 = vp[1];
  float d = a0.x * b0.x + a0.y * b0.y + a0.z * b0.z + a0.w * b0.w
          + a1.x * b1.x + a1.y * b1.y + a1.z * b1.z + a1.w * b1.w;
#pragma unroll
  for (int o = 32; o > 0; o >>= 1) d += __shfl_xor(d, o, 64);
  if (l == 0) out[row] = d;
}

__global__ void reduce_max(const float* __restrict__ v, float* __restrict__ outmax) {
  __shared__ float red[4];
  int t = threadIdx.x;
  float m = -3.0e38f;
  for (int j = t; j < 8192; j += 256) m = fmaxf(m, v[j]);
#pragma unroll
  for (int o = 32; o > 0; o >>= 1) m = fmaxf(m, __shfl_xor(m, o, 64));
  if ((t & 63) == 0) red[t >> 6] = m;
  __syncthreads();
  if (t == 0) outmax[0] = fmaxf(fmaxf(red[0], red[1]), fmaxf(red[2], red[3]));
}

__global__ void cvt4_bf16(const float* __restrict__ in, ushort* __restrict__ out) {
  int idx = blockIdx.x * 256 + threadIdx.x;
  float4 v = ((const float4*)in)[idx];
  ushort4 o; o.x = f2bf(v.x); o.y = f2bf(v.y); o.z = f2bf(v.z); o.w = f2bf(v.w);
  ((ushort4*)out)[idx] = o;
}

// wT_bf[f][c] = bf16(weight[c][f]); 512x512
__global__ void transpose_w(const float* __restrict__ w, ushort* __restrict__ wT) {
  __shared__ float tile[32][33];
  int t = threadIdx.x; int tx = t & 31, ty = t >> 5;
  int cb = (blockIdx.x & 15) * 32, fb = (blockIdx.x >> 4) * 32;
#pragma unroll
  for (int k = 0; k < 4; ++k) tile[ty + k * 8][tx] = w[(cb + ty + k * 8) * 512 + fb + tx];
  __syncthreads();
#pragma unroll
  for (int k = 0; k < 4; ++k) wT[(fb + ty + k * 8) * 512 + cb + tx] = f2bf(tile[tx][ty + k * 8]);
}

// WhmT[f][j] = sum_c neigh_bf[j][c] * wT_bf[f][c]   (bf16 out, transposed store)
__global__ __launch_bounds__(256, 4) void gemm_whmT(const ushort* __restrict__ A,
                                                    const ushort* __restrict__ B,
                                                    ushort* __restrict__ WhmT) {
  __shared__ ushort At[128 * 32];
  __shared__ ushort Bt2[128 * 32];
  int t = threadIdx.x;
  int j0 = (blockIdx.x >> 2) * 128, f0 = (blockIdx.x & 3) * 128;
  int w = t >> 6, l = t & 63, wr = w >> 1, wc = w & 1;
  f32x4 acc[4][4] = {};
  for (int it = 0; it < 16; ++it) {
    int k0 = it * 32;
#pragma unroll
    for (int c = 0; c < 2; ++c) {
      int u = c * 256 + t; int rr = u >> 2, p = u & 3;
      int sg = p ^ ((rr >> 1) & 3);
      load_lds16(A + (j0 + rr) * 512 + k0 + sg * 8, At + (c * 256 + (t & ~63)) * 8);
      load_lds16(B + (f0 + rr) * 512 + k0 + sg * 8, Bt2 + (c * 256 + (t & ~63)) * 8);
    }
    __syncthreads();
    bf16x8 af[4], bfr[4];
#pragma unroll
    for (int m = 0; m < 4; ++m) {
      int rr = wr * 64 + m * 16 + (l & 15);
      int q = (l >> 4) ^ ((rr >> 1) & 3);
      af[m] = *(const bf16x8*)(At + rr * 32 + q * 8);
    }
#pragma unroll
    for (int n = 0; n < 4; ++n) {
      int rb = wc * 64 + n * 16 + (l & 15);
      int q = (l >> 4) ^ ((rb >> 1) & 3);
      bfr[n] = *(const bf16x8*)(Bt2 + rb * 32 + q * 8);
    }
#pragma unroll
    for (int m = 0; m < 4; ++m)
#pragma unroll
      for (int n = 0; n < 4; ++n)
        acc[m][n] = __builtin_amdgcn_mfma_f32_16x16x32_bf16(af[m], bfr[n], acc[m][n], 0, 0, 0);
    __syncthreads();
  }
#pragma unroll
  for (int m = 0; m < 4; ++m)
#pragma unroll
    for (int n = 0; n < 4; ++n) {
      int j = j0 + wr * 64 + m * 16 + (l >> 4) * 4;
      int f = f0 + wc * 64 + n * 16 + (l & 15);
      ushort4 o;
      o.x = f2bf(acc[m][n][0]); o.y = f2bf(acc[m][n][1]);
      o.z = f2bf(acc[m][n][2]); o.w = f2bf(acc[m][n][3]);
      *(ushort4*)(WhmT + f * 8192 + j) = o;
    }
}

// ---------------------------------------------------------------------------
// Main fused kernel v3: BM=32, grid 512 (2 blocks/CU), B-frags direct
// global->VGPR (depth-1 prefetch), mask/s_m depth-2 prefetch, Pt double-
// buffered in LDS (4 KB), ONE raw s_barrier per iteration, no vmcnt drains.
//   num[s][i][f] = sum_{j in ksplit s} P[i][j]*Whm[j][f]; den[s][i]=sum_j P
//   P[i][j] = mask ? exp(lrelu(sn[i]+sm[j]) - m_i) : 0, m_i = lrelu(sn[i]+Smax)
// ---------------------------------------------------------------------------
__global__ __launch_bounds__(512, 4) void attn_main(
    const ushort* __restrict__ WhmT, const int* __restrict__ mask,
    const float* __restrict__ s_n, const float* __restrict__ s_m,
    const float* __restrict__ smaxp, float* __restrict__ num, float* __restrict__ den) {
  __shared__ ushort Pt[2][32 * 32];  // 2 x 2 KB, xor-swizzled [i][32j]
  int t = threadIdx.x;
  int bid = blockIdx.x;
  // XCD swizzle: each XCD handles one ksplit slice s (2 MB, L2-resident)
  int xcd = bid & 7;
  int s = xcd >> 1;
  int rblk = ((xcd & 1) << 6) | (bid >> 3);  // 0..127
  int i0 = rblk * 32;
  int kb = s * 2048;
  int w = t >> 6, l = t & 63;
  int i_loc = t >> 4, jt = t & 15;

  float sn = s_n[i0 + i_loc];
  float smx = smaxp[0];
  float mz = sn + smx;
  float m_i = mz > 0.f ? mz : 0.2f * mz;
  float miL = m_i * LOG2E;
  float dacc = 0.f;
  f32x4 acc[2][4] = {};

  // Pt write addr (2 bf16 per thread), xor-swizzled groups of 8
  int sgP = (jt >> 2) ^ ((i_loc >> 1) & 3);
  ushort* pw0 = &Pt[0][0] + i_loc * 32 + sgP * 8 + (jt & 3) * 2;
  ushort* pw1 = &Pt[1][0] + i_loc * 32 + sgP * 8 + (jt & 3) * 2;
  // af read addr: row (l&15)+16m, logical group l>>4; swz indep of m
  int qA = (l >> 4) ^ (((l & 15) >> 1) & 3);
  const ushort* ar0 = &Pt[0][0] + (l & 15) * 32 + qA * 8;
  const ushort* ar1 = &Pt[1][0] + (l & 15) * 32 + qA * 8;

  const int* mptr = mask + (size_t)(i0 + i_loc) * 8192 + kb + jt * 2;
  const float* sptr = s_m + kb + jt * 2;
  // B fragment base: lane reads Whm[k][f] for 8 consecutive k at fixed f
  const ushort* bfb[4];
#pragma unroll
  for (int n = 0; n < 4; ++n)
    bfb[n] = WhmT + (size_t)(w * 64 + n * 16 + (l & 15)) * 8192 + kb + (l >> 4) * 8;

#define P_COMP(mkv, svv, pdst, ACCUM)                                      \
  {                                                                        \
    float z0 = sn + (svv).x, z1 = sn + (svv).y;                            \
    float e0 = (z0 > 0.f ? z0 : 0.2f * z0) * LOG2E - miL;                  \
    float e1 = (z1 > 0.f ? z1 : 0.2f * z1) * LOG2E - miL;                  \
    float p0 = (mkv).x > 0 ? exp2f(e0) : 0.f;                              \
    float p1 = (mkv).y > 0 ? exp2f(e1) : 0.f;                              \
    ushort2 pv; pv.x = f2bf(p0); pv.y = f2bf(p1);                          \
    if (ACCUM) dacc += bf2f(pv.x) + bf2f(pv.y);                            \
    *(ushort2*)(pdst) = pv;                                                \
  }

  // body(it): read Pt[it&1] + BIN (tile it); write Pt[(it+1)&1] = P(it+1)
  // from MK/SV (issued 2 bodies ago); reload MK/SV for tile it+3;
  // prefetch BOUT = B-frags(it+1). One barrier at end.
#define BODY(IT, AR, PW, BIN, BOUT, MK, SV, VALIDP)                        \
  {                                                                        \
    int itc = (IT);                                                        \
    int kN = ((itc + 1) & 63) * 32;                                        \
    _Pragma("unroll") for (int n = 0; n < 4; ++n)                          \
      BOUT[n] = *(const bf16x8*)(bfb[n] + kN);                             \
    bf16x8 af0 = *(const bf16x8*)(AR);                                     \
    bf16x8 af1 = *(const bf16x8*)(AR + 512);                               \
    if (VALIDP) { P_COMP(MK, SV, PW, true); }                              \
    int kM = ((itc + 3) & 63) * 32;                                        \
    MK = *(const int2*)(mptr + kM);                                        \
    SV = *(const float2*)(sptr + kM);                                      \
    _Pragma("unroll") for (int n = 0; n < 4; ++n) {                        \
      acc[0][n] = __builtin_amdgcn_mfma_f32_16x16x32_bf16(af0, BIN[n], acc[0][n], 0, 0, 0); \
      acc[1][n] = __builtin_amdgcn_mfma_f32_16x16x32_bf16(af1, BIN[n], acc[1][n], 0, 0, 0); \
    }                                                                      \
    asm volatile("s_waitcnt lgkmcnt(0)" ::: "memory");                     \
    __builtin_amdgcn_sched_barrier(0);                                     \
    __builtin_amdgcn_s_barrier();                                          \
    __builtin_amdgcn_sched_barrier(0);                                     \
  }

  // ---- prologue ----
  bf16x8 bfrA[4], bfrB[4];
#pragma unroll
  for (int n = 0; n < 4; ++n) bfrA[n] = *(const bf16x8*)(bfb[n]);
  {
    int2 mk0 = *(const int2*)(mptr);
    float2 sv0 = *(const float2*)(sptr);
    P_COMP(mk0, sv0, pw0, true);
  }
  int2 mkA = *(const int2*)(mptr + 32);
  float2 svA = *(const float2*)(sptr + 32);
  int2 mkB = *(const int2*)(mptr + 64);
  float2 svB = *(const float2*)(sptr + 64);
  asm volatile("s_waitcnt lgkmcnt(0)" ::: "memory");
  __builtin_amdgcn_sched_barrier(0);
  __builtin_amdgcn_s_barrier();
  __builtin_amdgcn_sched_barrier(0);

  // ---- main loop: 64 iterations as 31 even/odd pairs + peeled tail ----
  for (int it2 = 0; it2 < 31; ++it2) {
    int it = it2 * 2;
    BODY(it,     ar0, pw1, bfrA, bfrB, mkA, svA, true);
    BODY(it + 1, ar1, pw0, bfrB, bfrA, mkB, svB, true);
  }
  BODY(62, ar0, pw1, bfrA, bfrB, mkA, svA, true);
  BODY(63, ar1, pw0, bfrB, bfrA, mkB, svB, false);

  // ---- denominator: 16 threads per row (within one wave) ----
  dacc += __shfl_xor(dacc, 8, 64);
  dacc += __shfl_xor(dacc, 4, 64);
  dacc += __shfl_xor(dacc, 2, 64);
  dacc += __shfl_xor(dacc, 1, 64);
  if ((t & 15) == 0) den[s * 4096 + i0 + i_loc] = dacc;
  // ---- partial numerator write (f32) ----
#pragma unroll
  for (int m = 0; m < 2; ++m)
#pragma unroll
    for (int n = 0; n < 4; ++n) {
      int i = i0 + m * 16 + (l >> 4) * 4;
      int f = w * 64 + n * 16 + (l & 15);
      float* dst = num + (size_t)(s * 4096 + i) * 512 + f;
      dst[0]       = acc[m][n][0];
      dst[512]     = acc[m][n][1];
      dst[2 * 512] = acc[m][n][2];
      dst[3 * 512] = acc[m][n][3];
    }
#undef BODY
#undef P_COMP
}

// out[i][f] = sum_s num[s][i][f] / sum_s den[s][i]
__global__ void reduce_out(const float* __restrict__ num, const float* __restrict__ den,
                           float* __restrict__ out) {
  int idx = blockIdx.x * 256 + threadIdx.x;  // 524288 threads
  int i = idx >> 7, f4 = (idx & 127) * 4;
  float4 a = *(const float4*)(num + (size_t)(0 * 4096 + i) * 512 + f4);
  float4 b = *(const float4*)(num + (size_t)(1 * 4096 + i) * 512 + f4);
  float4 c = *(const float4*)(num + (size_t)(2 * 4096 + i) * 512 + f4);
  float4 d = *(const float4*)(num + (size_t)(3 * 4096 + i) * 512 + f4);
  float dn = den[i] + den[4096 + i] + den[2 * 4096 + i] + den[3 * 4096 + i];
  float inv = 1.f / dn;
  float4 o;
  o.x = (a.x + b.x + c.x + d.x) * inv;
  o.y = (a.y + b.y + c.y + d.y) * inv;
  o.z = (a.z + b.z + c.z + d.z) * inv;
  o.w = (a.w + b.w + c.w + d.w) * inv;
  *(float4*)(out + (size_t)i * 512 + f4) = o;
}

extern "C" void kernel_launch(void* const* d_in, const int* in_sizes, int n_in,
                              void* d_out, int out_size, void* d_ws, size_t ws_size,
                              hipStream_t stream) {
  const float* node   = (const float*)d_in[0];
  const float* neigh  = (const float*)d_in[1];
  const float* weight = (const float*)d_in[2];
  const float* att    = (const float*)d_in[3];
  const int*   mask   = (const int*)d_in[4];
  float* out = (float*)d_out;

  char* ws = (char*)d_ws;
  float* w_a1 = (float*)ws;            // 512
  float* w_a2 = w_a1 + 512;            // 512
  float* s_n  = w_a2 + 512;            // 4096
  float* s_m  = s_n + 4096;            // 8192
  float* smax = s_m + 8192;            // 1
  ushort* neigh_bf = (ushort*)(ws + 64 * 1024);    // 8 MB
  ushort* wT_bf    = neigh_bf + 8192 * 512;        // 0.5 MB
  ushort* WhmT     = wT_bf + 512 * 512;            // 8 MB
  float*  num      = (float*)(WhmT + 512 * 8192);  // 32 MB
  float*  den      = num + 4 * 4096 * 512;         // 64 KB

  rowdot<<<128, 256, 0, stream>>>(weight, att, w_a1);
  rowdot<<<128, 256, 0, stream>>>(weight, att + 512, w_a2);
  rowdot<<<1024, 256, 0, stream>>>(node, w_a1, s_n);
  rowdot<<<2048, 256, 0, stream>>>(neigh, w_a2, s_m);
  reduce_max<<<1, 256, 0, stream>>>(s_m, smax);
  cvt4_bf16<<<4096, 256, 0, stream>>>(neigh, neigh_bf);
  transpose_w<<<256, 256, 0, stream>>>(weight, wT_bf);
  gemm_whmT<<<256, 256, 0, stream>>>(neigh_bf, wT_bf, WhmT);
  attn_main<<<512, 512, 0, stream>>>(WhmT, mask, s_n, s_m, smax, num, den);
  reduce_out<<<2048, 256, 0, stream>>>(num, den, out);
}